// Round 1
// baseline (279.887 us; speedup 1.0000x reference)
//
#include <hip/hip_runtime.h>

#define B_   8
#define N_   512
#define IND  256
#define H_   4
#define PH   32
#define OD   128   // H_*PH

typedef float v2f __attribute__((ext_vector_type(2)));

// leaky 0.4 * log2(e), and 0.6 * log2(e): logits in log2 domain -> v_exp_f32.
#define ATT_SCALE 0.5770780163555854f
#define DLR_SCALE 0.8656170245333781f

__device__ __forceinline__ float rflf(float x) {
    return __int_as_float(__builtin_amdgcn_readfirstlane(__float_as_int(x)));
}

__device__ __forceinline__ float fast_exp2(float x) {
#if __has_builtin(__builtin_amdgcn_exp2f)
    return __builtin_amdgcn_exp2f(x);
#else
    return exp2f(x);
#endif
}

// Packed fp32 FMA: d += a*b on both halves, ONE VOP3P instruction.
__device__ __forceinline__ void pk_fma(v2f& d, v2f a, v2f b) {
    asm("v_pk_fma_f32 %0, %1, %2, %0" : "+v"(d) : "v"(a), "v"(b));
}

// ---------------------------------------------------------------------------
// Kernel 1 v2: xl = x@Wl + bl ; xr = x@Wr + br  plus pre-scaled rank-1 parts.
// Retile: 4 rows x 4 cols per thread, K split in halves (ks), 1-deep prefetch.
// Halves ds_read_b128 and W-load instruction count per FMA vs the 2-col tile.
// grid 512, block 256: og(32 col-quads) x rr(2 row-halves) x ks(2 K-halves)
// x which(2: Wl/Wr). ks partners combine through padded LDS (scalar writes,
// stride 17 -> conflict-free).
// ---------------------------------------------------------------------------
__global__ __launch_bounds__(256, 2) void proj_kernel(
    const float* __restrict__ x,
    const float* __restrict__ Wl, const float* __restrict__ bl,
    const float* __restrict__ Wr, const float* __restrict__ br,
    const float* __restrict__ att,
    float* __restrict__ xl, float* __restrict__ xr,
    float* __restrict__ dl, float* __restrict__ dr)
{
    __shared__ float xs[8 * IND];        // 8 KB
    __shared__ float comb[128][17];      // 8.7 KB, pad -> conflict-free

    const int t = threadIdx.x;
    const int row0 = blockIdx.x * 8;

    const float4* xp4 = (const float4*)(x + (size_t)row0 * IND);
    float4* xs4 = (float4*)xs;
    xs4[t]       = xp4[t];
    xs4[t + 256] = xp4[t + 256];
    __syncthreads();

    const int og    = t & 31;        // col quad: cols og*4 .. og*4+3
    const int rr    = (t >> 5) & 1;  // row half: rows rr*4 .. rr*4+3
    const int ks    = (t >> 6) & 1;  // K half:   k0 = ks*128
    const int which = t >> 7;        // 0: Wl->xl/dl, 1: Wr->xr/dr
    const int o0 = og * 4;
    const int r0 = rr * 4;
    const int k0 = ks * 128;
    const float* W = which ? Wr : Wl;

    float acc[4][4];
    #pragma unroll
    for (int r = 0; r < 4; ++r)
        #pragma unroll
        for (int c = 0; c < 4; ++c) acc[r][c] = 0.f;

    const float* wp = W + (size_t)k0 * OD + o0;

    float wc[4][4], xc[4][4];
    #pragma unroll
    for (int kk = 0; kk < 4; ++kk)
        *(float4*)wc[kk] = *(const float4*)(wp + (size_t)kk * OD);
    #pragma unroll
    for (int r = 0; r < 4; ++r)
        *(float4*)xc[r] = *(const float4*)(&xs[(r0 + r) * IND + k0]);

    #pragma unroll 4
    for (int s = 0; s < 32; ++s) {
        float wn[4][4], xn[4][4];
        if (s < 31) {
            const float* wq = wp + (size_t)(s + 1) * 4 * OD;
            #pragma unroll
            for (int kk = 0; kk < 4; ++kk)
                *(float4*)wn[kk] = *(const float4*)(wq + (size_t)kk * OD);
            const int kb = k0 + (s + 1) * 4;
            #pragma unroll
            for (int r = 0; r < 4; ++r)
                *(float4*)xn[r] = *(const float4*)(&xs[(r0 + r) * IND + kb]);
        }
        #pragma unroll
        for (int kk = 0; kk < 4; ++kk)
            #pragma unroll
            for (int r = 0; r < 4; ++r)
                #pragma unroll
                for (int c = 0; c < 4; ++c)
                    acc[r][c] = fmaf(xc[r][kk], wc[kk][c], acc[r][c]);
        #pragma unroll
        for (int kk = 0; kk < 4; ++kk) *(float4*)wc[kk] = *(float4*)wn[kk];
        #pragma unroll
        for (int r = 0; r < 4; ++r)    *(float4*)xc[r]  = *(float4*)xn[r];
    }

    // combine K-halves: ks=1 stages partials, ks=0 sums + writes everything
    const int pid = (t & 63) | ((t & 128) >> 1);   // which<<6 | rr<<5 | og
    if (ks == 1) {
        #pragma unroll
        for (int i = 0; i < 16; ++i) comb[pid][i] = acc[i >> 2][i & 3];
    }
    __syncthreads();
    if (ks == 0) {
        const float* bb  = which ? br : bl;
        float* dst = which ? xr : xl;
        float* dp  = which ? dr : dl;
        float4 bv = *(const float4*)(bb + o0);
        float4 av = *(const float4*)(att + o0);
        const float bvf[4] = {bv.x, bv.y, bv.z, bv.w};
        const float avf[4] = {av.x, av.y, av.z, av.w};
        #pragma unroll
        for (int r = 0; r < 4; ++r) {
            float y[4];
            #pragma unroll
            for (int c = 0; c < 4; ++c)
                y[c] = (acc[r][c] + comb[pid][r * 4 + c]) + bvf[c];
            *(float4*)(&dst[(size_t)(row0 + r0 + r) * OD + o0]) =
                make_float4(y[0], y[1], y[2], y[3]);
            // rank-1 part: dl/dr[n,h] = 0.6*log2e * sum_c att[h,c]*y[c]
            float dc = fmaf(avf[0], y[0], fmaf(avf[1], y[1],
                       fmaf(avf[2], y[2], avf[3] * y[3])));
            dc += __shfl_xor(dc, 1);
            dc += __shfl_xor(dc, 2);
            dc += __shfl_xor(dc, 4);   // sums the 8 og-lanes of one head
            if ((og & 7) == 0)
                dp[(size_t)(row0 + r0 + r) * H_ + (og >> 3)] = DLR_SCALE * dc;
        }
    }
}

// ---------------------------------------------------------------------------
// Kernel 2 v2: masked-softmax attention aggregate, FULL-ROW threads.
// grid B*N = 4096 (one block per target i), block 256 = 4 waves (one head per
// wave). lane = j-slice; each thread owns ALL 32 channels of its head.
// xr fragment, scaled att, and dr are wave-uniform -> forced into SGPRs via
// readfirstlane: the e2 FMAs read them as the one legal SGPR operand, so the
// whole i-side state costs zero VGPRs. No DPP combine, exp2/mask/sumw once
// per (i,j) (was 4x across cq lanes). j-loop: 8 strips of 64.
// Epilogue: stride-33 padded LDS transpose (conflict-free) + half-wave sum.
// blockIdx swizzle pins batch b to one XCD so adj/xl slices stay L2-local.
// ---------------------------------------------------------------------------
__global__ __launch_bounds__(256, 4) void attn_kernel(
    const int* __restrict__ adj, const float* __restrict__ att,
    const float* __restrict__ bias,
    const float* __restrict__ xl, const float* __restrict__ xr,
    const float* __restrict__ dl, const float* __restrict__ dr,
    float* __restrict__ out)
{
    __shared__ float sacc[H_][64][PH + 1];   // 33792 B -> 4 blocks/CU

    const int t = threadIdx.x;
    // batch<->XCD affinity: consecutive blockIdx round-robins XCDs, so map
    // XCD k -> batch k (4096 = 8 XCD * 512 blocks).
    const int bid = (blockIdx.x & 7) * (B_ * N_ / 8) + (blockIdx.x >> 3);
    const int b    = bid >> 9;
    const int i0   = bid & (N_ - 1);
    const int lane = t & 63;
    const int h    = __builtin_amdgcn_readfirstlane(t >> 6);
    const int cbase = h * PH;

    // wave-uniform i-side state -> SGPRs
    float xrS[PH], atS[PH];
    {
        const float* xp = xr + ((size_t)(b * N_ + i0)) * OD + cbase;
        const float* ap = att + cbase;
        #pragma unroll
        for (int q = 0; q < 8; ++q) {
            float4 v = *(const float4*)(xp + q * 4);
            float4 a = *(const float4*)(ap + q * 4);
            xrS[q * 4 + 0] = rflf(v.x); xrS[q * 4 + 1] = rflf(v.y);
            xrS[q * 4 + 2] = rflf(v.z); xrS[q * 4 + 3] = rflf(v.w);
            atS[q * 4 + 0] = rflf(ATT_SCALE * a.x);
            atS[q * 4 + 1] = rflf(ATT_SCALE * a.y);
            atS[q * 4 + 2] = rflf(ATT_SCALE * a.z);
            atS[q * 4 + 3] = rflf(ATT_SCALE * a.w);
        }
    }
    const float drS = rflf(dr[((size_t)(b * N_ + i0)) * H_ + h]);

    v2f acc[16];
    #pragma unroll
    for (int m = 0; m < 16; ++m) acc[m] = (v2f){0.f, 0.f};
    float sumw = 0.f;

    const float* xlp = xl + ((size_t)(b * N_ + lane)) * OD + cbase;
    const int*   ajp = adj + ((size_t)(b * N_ + lane)) * N_ + i0;
    const float* dlp = dl + ((size_t)(b * N_ + lane)) * H_ + h;

    #pragma unroll
    for (int u = 0; u < 8; ++u) {
        float4 xq[8];
        #pragma unroll
        for (int q = 0; q < 8; ++q)
            xq[q] = *(const float4*)(xlp + (size_t)u * 64 * OD + q * 4);
        const int   aj = ajp[(size_t)u * 64 * N_];
        const float wd = dlp[(size_t)u * 64 * H_];

        // e2 = sum_c atS[c] * |xrS[c] + xl[j][c]|, 4 independent FMA chains
        float e0 = 0.f, e1 = 0.f, e2 = 0.f, e3 = 0.f;
        #pragma unroll
        for (int q = 0; q < 8; ++q) {
            float s0 = xrS[q * 4 + 0] + xq[q].x;
            float s1 = xrS[q * 4 + 1] + xq[q].y;
            float s2 = xrS[q * 4 + 2] + xq[q].z;
            float s3 = xrS[q * 4 + 3] + xq[q].w;
            e0 = fmaf(atS[q * 4 + 0], __builtin_fabsf(s0), e0);
            e1 = fmaf(atS[q * 4 + 1], __builtin_fabsf(s1), e1);
            e2 = fmaf(atS[q * 4 + 2], __builtin_fabsf(s2), e2);
            e3 = fmaf(atS[q * 4 + 3], __builtin_fabsf(s3), e3);
        }
        float e = ((wd + drS) + (e0 + e1)) + (e2 + e3);   // log2-domain logit
        const int j = u * 64 + lane;
        bool keep = (aj != 0) || (j == i0);               // forced self-loop
        float w = keep ? fast_exp2(e) : 0.f;
        sumw += w;
        v2f ws = (v2f){w, w};
        #pragma unroll
        for (int q = 0; q < 8; ++q) {
            pk_fma(acc[q * 2 + 0], ws, (v2f){xq[q].x, xq[q].y});
            pk_fma(acc[q * 2 + 1], ws, (v2f){xq[q].z, xq[q].w});
        }
    }

    // denominator: full 64-lane butterfly
    #pragma unroll
    for (int m = 1; m < 64; m <<= 1) sumw += __shfl_xor(sumw, m);
    const float inv = 1.f / sumw;

    // transpose-reduce over the 64 j-slices; stride 33 => bank-conflict-free
    #pragma unroll
    for (int m = 0; m < 16; ++m) {
        sacc[h][lane][2 * m]     = acc[m].x;
        sacc[h][lane][2 * m + 1] = acc[m].y;
    }
    __syncthreads();

    const int c  = lane & 31;
    const int hf = lane >> 5;
    float s0 = 0.f, s1 = 0.f, s2 = 0.f, s3 = 0.f;
    #pragma unroll
    for (int k = 0; k < 32; k += 4) {
        s0 += sacc[h][hf * 32 + k + 0][c];
        s1 += sacc[h][hf * 32 + k + 1][c];
        s2 += sacc[h][hf * 32 + k + 2][c];
        s3 += sacc[h][hf * 32 + k + 3][c];
    }
    float s = (s0 + s1) + (s2 + s3);
    s += __shfl_xor(s, 32);
    if (hf == 0) {
        const int cg = cbase + c;
        out[((size_t)(b * N_ + i0)) * OD + cg] = fmaf(s, inv, bias[cg]);
    }
}

extern "C" void kernel_launch(void* const* d_in, const int* in_sizes, int n_in,
                              void* d_out, int out_size, void* d_ws, size_t ws_size,
                              hipStream_t stream) {
    const float* x    = (const float*)d_in[0];
    const int*   adj  = (const int*)d_in[1];
    const float* Wl   = (const float*)d_in[2];
    const float* bl   = (const float*)d_in[3];
    const float* Wr   = (const float*)d_in[4];
    const float* br   = (const float*)d_in[5];
    const float* att  = (const float*)d_in[6];
    const float* bias = (const float*)d_in[7];
    float* out = (float*)d_out;

    float* xl = (float*)d_ws;                    // 2 MB
    float* xr = xl + (size_t)B_ * N_ * OD;       // 2 MB
    float* dl = xr + (size_t)B_ * N_ * OD;       // 64 KB
    float* dr = dl + (size_t)B_ * N_ * H_;       // 64 KB

    proj_kernel<<<512, 256, 0, stream>>>(x, Wl, bl, Wr, br, att, xl, xr, dl, dr);
    attn_kernel<<<4096, 256, 0, stream>>>(adj, att, bias, xl, xr, dl, dr, out);
}

// Round 2
// 210.244 us; speedup vs baseline: 1.3312x; 1.3312x over previous
//
#include <hip/hip_runtime.h>

#define B_   8
#define N_   512
#define IND  256
#define H_   4
#define PH   32
#define OD   128   // H_*PH
#define TI   2     // targets per block (attn)

typedef float v2f __attribute__((ext_vector_type(2)));

// leaky 0.4 * log2(e), and 0.6 * log2(e): logits in log2 domain -> v_exp_f32.
#define ATT_SCALE 0.5770780163555854f
#define DLR_SCALE 0.8656170245333781f

template <int PAT>
__device__ __forceinline__ float dpp_add(float x) {
    int yi = __builtin_amdgcn_mov_dpp(__float_as_int(x), PAT, 0xF, 0xF, true);
    return x + __int_as_float(yi);
}

__device__ __forceinline__ float fast_exp2(float x) {
#if __has_builtin(__builtin_amdgcn_exp2f)
    return __builtin_amdgcn_exp2f(x);
#else
    return exp2f(x);
#endif
}

// Packed fp32 FMA: d += a*b on both halves, ONE VOP3P instruction.
__device__ __forceinline__ void pk_fma(v2f& d, v2f a, v2f b) {
    asm("v_pk_fma_f32 %0, %1, %2, %0" : "+v"(d) : "v"(a), "v"(b));
}

// ---------------------------------------------------------------------------
// Kernel 1 v3: xl = x@Wl + bl ; xr = x@Wr + br  plus pre-scaled rank-1 parts.
// rows=4/block, grid 1024 -> 4 blocks/CU (16 waves/CU) vs v2's 2 blocks/CU.
// Thread = 1 row x 4 cols rank-1 update; x read direct from global (4-lane
// r-groups broadcast-merge, row is L1-resident); W float4 loads broadcast
// across the 4 r-lanes. Parity double-buffer under #pragma unroll 2 ->
// static indices (no scratch, rule #20) and no wc=wn register-copy tax.
// No LDS, no barriers.
// ---------------------------------------------------------------------------
__global__ __launch_bounds__(256, 4) void proj_kernel(
    const float* __restrict__ x,
    const float* __restrict__ Wl, const float* __restrict__ bl,
    const float* __restrict__ Wr, const float* __restrict__ br,
    const float* __restrict__ att,
    float* __restrict__ xl, float* __restrict__ xr,
    float* __restrict__ dl, float* __restrict__ dr)
{
    const int t = threadIdx.x;
    const int row0 = blockIdx.x * 4;

    const int r     = t & 3;         // row within block (lane bits 0-1)
    const int og    = (t >> 2) & 31; // col quad (lane bits 2-5 + wave bit)
    const int which = t >> 7;        // 0: Wl->xl/dl, 1: Wr->xr/dr
    const int o0 = og * 4;
    const float* W = (which ? Wr : Wl) + o0;
    const float* xrow = x + (size_t)(row0 + r) * IND;

    float acc[4] = {0.f, 0.f, 0.f, 0.f};

    float4 wb[2][4];
    float4 xb[2];
    #pragma unroll
    for (int kk = 0; kk < 4; ++kk)
        wb[0][kk] = *(const float4*)(W + (size_t)kk * OD);
    xb[0] = *(const float4*)(xrow);

    #pragma unroll 2
    for (int s = 0; s < 64; ++s) {           // 64 chunks of 4 k
        const int cur = s & 1, nxt = cur ^ 1;
        if (s < 63) {
            const float* Wq = W + (size_t)((s + 1) * 4) * OD;
            #pragma unroll
            for (int kk = 0; kk < 4; ++kk)
                wb[nxt][kk] = *(const float4*)(Wq + (size_t)kk * OD);
            xb[nxt] = *(const float4*)(xrow + (s + 1) * 4);
        }
        const float xk[4] = {xb[cur].x, xb[cur].y, xb[cur].z, xb[cur].w};
        #pragma unroll
        for (int kk = 0; kk < 4; ++kk) {
            acc[0] = fmaf(xk[kk], wb[cur][kk].x, acc[0]);
            acc[1] = fmaf(xk[kk], wb[cur][kk].y, acc[1]);
            acc[2] = fmaf(xk[kk], wb[cur][kk].z, acc[2]);
            acc[3] = fmaf(xk[kk], wb[cur][kk].w, acc[3]);
        }
    }

    const float* bb = which ? br : bl;
    float* dst = which ? xr : xl;
    float* dp  = which ? dr : dl;
    float4 bv = *(const float4*)(bb + o0);
    float4 av = *(const float4*)(att + o0);
    const float y0 = acc[0] + bv.x;
    const float y1 = acc[1] + bv.y;
    const float y2 = acc[2] + bv.z;
    const float y3 = acc[3] + bv.w;
    *(float4*)(&dst[(size_t)(row0 + r) * OD + o0]) = make_float4(y0, y1, y2, y3);

    // rank-1 part: dl/dr[n,h] = 0.6*log2e * sum_c att[h,c]*y[c]
    // reduce over the 8 og-lane-groups of one head (lane bits 2-4)
    float dc = fmaf(av.x, y0, fmaf(av.y, y1, fmaf(av.z, y2, av.w * y3)));
    dc += __shfl_xor(dc, 4);
    dc += __shfl_xor(dc, 8);
    dc += __shfl_xor(dc, 16);
    if (((t >> 2) & 7) == 0)
        dp[(size_t)(row0 + r) * H_ + (og >> 3)] = DLR_SCALE * dc;
}

// ---------------------------------------------------------------------------
// Kernel 2 v3: masked-softmax attention aggregate. Round-0's proven lane
// layout (cq = t&3 owns 8 ch, js = (t>>2)&15 j-slices, h = t>>6) -- coalesced
// xl/adj loads, NO per-thread big arrays (round-1's spill disaster reverted).
// Changes vs round-0:
//   * TI 4 -> 2, grid 2048: LDS 33.8 -> 17.4 KB, VGPR ~70 -> ~7 blocks/CU
//     resident (was 4) => double the wave supply for latency hiding.
//   * epilogue LDS dims reordered [h][il][js][PH+1]: write banks (js+8cq)%32
//     = 2-way (free, was 16-way / 262K conflict cycles); reads conflict-free.
//   * XCD<->batch affinity swizzle kept (2048 = 8 XCD x 256).
// ---------------------------------------------------------------------------
__global__ __launch_bounds__(256, 6) void attn_kernel(
    const int* __restrict__ adj, const float* __restrict__ att,
    const float* __restrict__ bias,
    const float* __restrict__ xl, const float* __restrict__ xr,
    const float* __restrict__ dl, const float* __restrict__ dr,
    float* __restrict__ out)
{
    __shared__ float sacc[H_][TI][16][PH + 1];  // 16.9 KB, 2-way write banks
    __shared__ float ssum[H_][16][TI];          // 0.5 KB

    const int t = threadIdx.x;
    const int bid = (blockIdx.x & 7) * 256 + (blockIdx.x >> 3);
    const int b  = bid >> 8;
    const int i0 = (bid & 255) * TI;
    const int cq = t & 3;
    const int js = (t >> 2) & 15;
    const int h  = t >> 6;
    const int cbase = h * PH + cq * 8;

    // preload att (pre-scaled by 0.4*log2e) and xr fragments for the targets
    float atS[8];
    {
        const float* ap = att + cbase;
        float4 a0 = *(const float4*)(ap);
        float4 a1 = *(const float4*)(ap + 4);
        atS[0] = ATT_SCALE * a0.x; atS[1] = ATT_SCALE * a0.y;
        atS[2] = ATT_SCALE * a0.z; atS[3] = ATT_SCALE * a0.w;
        atS[4] = ATT_SCALE * a1.x; atS[5] = ATT_SCALE * a1.y;
        atS[6] = ATT_SCALE * a1.z; atS[7] = ATT_SCALE * a1.w;
    }
    float xrS[TI][8];
    float drv[TI];
    #pragma unroll
    for (int il = 0; il < TI; ++il) {
        const float* xp = xr + ((size_t)(b * N_ + i0 + il)) * OD + cbase;
        float4 r0 = *(const float4*)(xp);
        float4 r1 = *(const float4*)(xp + 4);
        xrS[il][0] = r0.x; xrS[il][1] = r0.y; xrS[il][2] = r0.z; xrS[il][3] = r0.w;
        xrS[il][4] = r1.x; xrS[il][5] = r1.y; xrS[il][6] = r1.z; xrS[il][7] = r1.w;
        drv[il] = dr[((size_t)(b * N_ + i0 + il)) * H_ + h];  // pre-scaled
    }

    v2f acc[TI][4];
    float sumw[TI];
    #pragma unroll
    for (int il = 0; il < TI; ++il) {
        sumw[il] = 0.f;
        #pragma unroll
        for (int m = 0; m < 4; ++m) acc[il][m] = (v2f){0.f, 0.f};
    }

    // software-pipelined j-loop: j = u*16 + js, u = 0..31
    const float* xlp = xl + ((size_t)(b * N_ + js)) * OD + cbase;
    const int*   ajp = adj + ((size_t)(b * N_ + js)) * N_ + i0;
    const float* dlp = dl + ((size_t)(b * N_ + js)) * H_ + h;

    float4 va = *(const float4*)(xlp);
    float4 vb = *(const float4*)(xlp + 4);
    int2   mj = *(const int2*)(ajp);
    float  dj = *dlp;

    #pragma unroll 2
    for (int u = 0; u < 32; ++u) {
        float4 wa = va, wb = vb;
        int2   wm = mj;
        float  wd = dj;
        if (u < 31) {
            xlp += 16 * OD; ajp += 16 * N_; dlp += 16 * H_;
            va = *(const float4*)(xlp);
            vb = *(const float4*)(xlp + 4);
            mj = *(const int2*)(ajp);
            dj = *dlp;
        }
        const int j = u * 16 + js;
        v2f p0 = (v2f){wa.x, wa.y}, p1 = (v2f){wa.z, wa.w};
        v2f p2 = (v2f){wb.x, wb.y}, p3 = (v2f){wb.z, wb.w};
        int wmv[TI] = {wm.x, wm.y};
        #pragma unroll
        for (int il = 0; il < TI; ++il) {
            float s, e2a = 0.f, e2b = 0.f;
            s = xrS[il][0] + wa.x; e2a = fmaf(atS[0], __builtin_fabsf(s), e2a);
            s = xrS[il][1] + wa.y; e2b = fmaf(atS[1], __builtin_fabsf(s), e2b);
            s = xrS[il][2] + wa.z; e2a = fmaf(atS[2], __builtin_fabsf(s), e2a);
            s = xrS[il][3] + wa.w; e2b = fmaf(atS[3], __builtin_fabsf(s), e2b);
            s = xrS[il][4] + wb.x; e2a = fmaf(atS[4], __builtin_fabsf(s), e2a);
            s = xrS[il][5] + wb.y; e2b = fmaf(atS[5], __builtin_fabsf(s), e2b);
            s = xrS[il][6] + wb.z; e2a = fmaf(atS[6], __builtin_fabsf(s), e2a);
            s = xrS[il][7] + wb.w; e2b = fmaf(atS[7], __builtin_fabsf(s), e2b);
            float eh = e2a + e2b;
            eh = dpp_add<0xB1>(eh);          // + lane^1 (quad_perm 1,0,3,2)
            eh = dpp_add<0x4E>(eh);          // + lane^2 (quad_perm 2,3,0,1)
            float e = (wd + drv[il]) + eh;   // full log2-domain logit
            bool keep = (wmv[il] != 0) || (j == i0 + il);
            float w = keep ? fast_exp2(e) : 0.f;
            sumw[il] += w;
            v2f ws = (v2f){w, w};
            pk_fma(acc[il][0], ws, p0);
            pk_fma(acc[il][1], ws, p1);
            pk_fma(acc[il][2], ws, p2);
            pk_fma(acc[il][3], ws, p3);
        }
    }

    // ---- epilogue: LDS transpose + reduce over the 16 js slices ----
    #pragma unroll
    for (int il = 0; il < TI; ++il) {
        float4 w0 = make_float4(acc[il][0].x, acc[il][0].y,
                                acc[il][1].x, acc[il][1].y);
        float4 w1 = make_float4(acc[il][2].x, acc[il][2].y,
                                acc[il][3].x, acc[il][3].y);
        *(float4*)(&sacc[h][il][js][cq * 8])     = w0;
        *(float4*)(&sacc[h][il][js][cq * 8 + 4]) = w1;
    }
    if (cq == 0) {
        #pragma unroll
        for (int il = 0; il < TI; ++il)
            ssum[h][js][il] = sumw[il];
    }
    __syncthreads();

    const int lane = t & 63;
    const int il2  = lane >> 5;      // target within block
    const int c    = lane & 31;      // channel within head
    float st = 0.f;
    #pragma unroll
    for (int k = 0; k < 16; ++k) st += ssum[h][k][il2];
    float a = 0.f;
    #pragma unroll
    for (int k = 0; k < 16; ++k) a += sacc[h][il2][k][c];
    const float inv = 1.f / st;
    const int cg = h * PH + c;
    out[((size_t)(b * N_ + i0 + il2)) * OD + cg] = fmaf(a, inv, bias[cg]);
}

extern "C" void kernel_launch(void* const* d_in, const int* in_sizes, int n_in,
                              void* d_out, int out_size, void* d_ws, size_t ws_size,
                              hipStream_t stream) {
    const float* x    = (const float*)d_in[0];
    const int*   adj  = (const int*)d_in[1];
    const float* Wl   = (const float*)d_in[2];
    const float* bl   = (const float*)d_in[3];
    const float* Wr   = (const float*)d_in[4];
    const float* br   = (const float*)d_in[5];
    const float* att  = (const float*)d_in[6];
    const float* bias = (const float*)d_in[7];
    float* out = (float*)d_out;

    float* xl = (float*)d_ws;                    // 2 MB
    float* xr = xl + (size_t)B_ * N_ * OD;       // 2 MB
    float* dl = xr + (size_t)B_ * N_ * OD;       // 64 KB
    float* dr = dl + (size_t)B_ * N_ * H_;       // 64 KB

    proj_kernel<<<1024, 256, 0, stream>>>(x, Wl, bl, Wr, br, att, xl, xr, dl, dr);
    attn_kernel<<<2048, 256, 0, stream>>>(adj, att, bias, xl, xr, dl, dr, out);
}

// Round 3
// 123.586 us; speedup vs baseline: 2.2647x; 1.7012x over previous
//
#include <hip/hip_runtime.h>

#define B_   8
#define N_   512
#define IND  256
#define H_   4
#define PH   32
#define OD   128   // H_*PH
#define TI   2     // targets per block (attn)

typedef float v2f __attribute__((ext_vector_type(2)));

// leaky 0.4 * log2(e), and 0.6 * log2(e): logits in log2 domain -> v_exp_f32.
#define ATT_SCALE 0.5770780163555854f
#define DLR_SCALE 0.8656170245333781f

template <int PAT>
__device__ __forceinline__ float dpp_add(float x) {
    int yi = __builtin_amdgcn_mov_dpp(__float_as_int(x), PAT, 0xF, 0xF, true);
    return x + __int_as_float(yi);
}

__device__ __forceinline__ float fast_exp2(float x) {
#if __has_builtin(__builtin_amdgcn_exp2f)
    return __builtin_amdgcn_exp2f(x);
#else
    return exp2f(x);
#endif
}

// Packed fp32 FMA: d += a*b on both halves, ONE VOP3P instruction.
__device__ __forceinline__ void pk_fma(v2f& d, v2f a, v2f b) {
    asm("v_pk_fma_f32 %0, %1, %2, %0" : "+v"(d) : "v"(a), "v"(b));
}

// ---------------------------------------------------------------------------
// Kernel 1 v4: xl = x@Wl + bl ; xr = x@Wr + br  plus pre-scaled rank-1 parts.
// v2's proven 8-row LDS tile, but block = 512 threads with K quartered (ks):
// v2's limiter was grid 512 @ 256 threads = 2 blocks/CU = 8 waves/CU of
// available work; now 2 blocks/CU = 16 waves/CU. Each W element still loaded
// exactly once per block (ks quarters are disjoint), so W/L2 traffic HALVES
// vs v2. Thread = 4 rows x 4 cols x 64 k. K-quarter combine via padded LDS
// (stride 17, 2-way banks = free). W double-buffered (parity, static idx);
// x read from LDS at use (broadcast; 4-wave TLP covers the latency).
// VGPR cap rule (r1/r2 post-mortem): cap ~= 256/min_waves -> use (512,2)=128.
// ---------------------------------------------------------------------------
__global__ __launch_bounds__(512, 2) void proj_kernel(
    const float* __restrict__ x,
    const float* __restrict__ Wl, const float* __restrict__ bl,
    const float* __restrict__ Wr, const float* __restrict__ br,
    const float* __restrict__ att,
    float* __restrict__ xl, float* __restrict__ xr,
    float* __restrict__ dl, float* __restrict__ dr)
{
    __shared__ float xs[8 * IND];        // 8 KB
    __shared__ float comb[3][128][17];   // 25.5 KB, pad -> conflict-free

    const int t = threadIdx.x;
    const int row0 = blockIdx.x * 8;

    ((float4*)xs)[t] = ((const float4*)(x + (size_t)row0 * IND))[t];
    __syncthreads();

    const int og    = t & 31;        // col quad: cols og*4 .. og*4+3
    const int rr    = (t >> 5) & 1;  // row half: rows rr*4 .. rr*4+3
    const int ks    = (t >> 6) & 3;  // K quarter: k0 = ks*64 (wave-uniform)
    const int which = t >> 8;        // 0: Wl->xl/dl, 1: Wr->xr/dr
    const int o0 = og * 4;
    const int r0 = rr * 4;
    const int k0 = ks * 64;
    const float* W = (which ? Wr : Wl) + (size_t)k0 * OD + o0;

    float acc[4][4];
    #pragma unroll
    for (int r = 0; r < 4; ++r)
        #pragma unroll
        for (int c = 0; c < 4; ++c) acc[r][c] = 0.f;

    float4 wb[2][4];
    #pragma unroll
    for (int kk = 0; kk < 4; ++kk)
        wb[0][kk] = *(const float4*)(W + (size_t)kk * OD);

    #pragma unroll 2
    for (int s = 0; s < 16; ++s) {       // 16 chunks of 4 k (K=64 per thread)
        const int cur = s & 1, nxt = cur ^ 1;
        if (s < 15) {
            const float* Wq = W + (size_t)((s + 1) * 4) * OD;
            #pragma unroll
            for (int kk = 0; kk < 4; ++kk)
                wb[nxt][kk] = *(const float4*)(Wq + (size_t)kk * OD);
        }
        float xv[4][4];
        #pragma unroll
        for (int r = 0; r < 4; ++r)
            *(float4*)(xv[r]) = *(const float4*)(&xs[(r0 + r) * IND + k0 + s * 4]);
        #pragma unroll
        for (int kk = 0; kk < 4; ++kk)
            #pragma unroll
            for (int r = 0; r < 4; ++r) {
                acc[r][0] = fmaf(xv[r][kk], wb[cur][kk].x, acc[r][0]);
                acc[r][1] = fmaf(xv[r][kk], wb[cur][kk].y, acc[r][1]);
                acc[r][2] = fmaf(xv[r][kk], wb[cur][kk].z, acc[r][2]);
                acc[r][3] = fmaf(xv[r][kk], wb[cur][kk].w, acc[r][3]);
            }
    }

    // combine K-quarters: ks=1..3 stage partials, ks=0 sums + writes
    const int pid = og | (rr << 5) | (which << 6);   // 0..127
    if (ks != 0) {
        #pragma unroll
        for (int i = 0; i < 16; ++i)
            comb[ks - 1][pid][i] = acc[i >> 2][i & 3];
    }
    __syncthreads();
    if (ks == 0) {
        const float* bb = which ? br : bl;
        float* dst = which ? xr : xl;
        float* dp  = which ? dr : dl;
        float4 bv = *(const float4*)(bb + o0);
        float4 av = *(const float4*)(att + o0);
        const float bvf[4] = {bv.x, bv.y, bv.z, bv.w};
        const float avf[4] = {av.x, av.y, av.z, av.w};
        #pragma unroll
        for (int r = 0; r < 4; ++r) {
            float y[4];
            #pragma unroll
            for (int c = 0; c < 4; ++c)
                y[c] = ((acc[r][c] + comb[0][pid][r * 4 + c])
                      + (comb[1][pid][r * 4 + c] + comb[2][pid][r * 4 + c]))
                      + bvf[c];
            *(float4*)(&dst[(size_t)(row0 + r0 + r) * OD + o0]) =
                make_float4(y[0], y[1], y[2], y[3]);
            // rank-1 part: dl/dr[n,h] = 0.6*log2e * sum_c att[h,c]*y[c]
            float dc = fmaf(avf[0], y[0], fmaf(avf[1], y[1],
                       fmaf(avf[2], y[2], avf[3] * y[3])));
            dc += __shfl_xor(dc, 1);
            dc += __shfl_xor(dc, 2);
            dc += __shfl_xor(dc, 4);   // sums the 8 og-lanes of one head
            if ((og & 7) == 0)
                dp[(size_t)(row0 + r0 + r) * H_ + (og >> 3)] = DLR_SCALE * dc;
        }
    }
}

// ---------------------------------------------------------------------------
// Kernel 2 v4: identical algorithm to v3 (which PASSED; its FETCH dropped
// 42->19 MB from the XCD swizzle and bank conflicts hit 0), with ONE change:
// __launch_bounds__(256,3). Empirical toolchain rule from r1/r2 post-mortems:
// VGPR cap ~= 256/min_waves. (256,6) capped at 40 -> 42 MB of scratch spill
// (WRITE_SIZE counter) and 2x slowdown. (256,3) caps at ~85; the kernel needs
// ~55 -> no spill, and HW occupancy is then set by actual VGPR use
// (<=64 -> 8 waves/SIMD; LDS 17.4 KB -> 9 blocks), grid supplies 8 blocks/CU.
// ---------------------------------------------------------------------------
__global__ __launch_bounds__(256, 3) void attn_kernel(
    const int* __restrict__ adj, const float* __restrict__ att,
    const float* __restrict__ bias,
    const float* __restrict__ xl, const float* __restrict__ xr,
    const float* __restrict__ dl, const float* __restrict__ dr,
    float* __restrict__ out)
{
    __shared__ float sacc[H_][TI][16][PH + 1];  // 16.9 KB, 2-way write banks
    __shared__ float ssum[H_][16][TI];          // 0.5 KB

    const int t = threadIdx.x;
    const int bid = (blockIdx.x & 7) * 256 + (blockIdx.x >> 3);
    const int b  = bid >> 8;
    const int i0 = (bid & 255) * TI;
    const int cq = t & 3;
    const int js = (t >> 2) & 15;
    const int h  = t >> 6;
    const int cbase = h * PH + cq * 8;

    // preload att (pre-scaled by 0.4*log2e) and xr fragments for the targets
    float atS[8];
    {
        const float* ap = att + cbase;
        float4 a0 = *(const float4*)(ap);
        float4 a1 = *(const float4*)(ap + 4);
        atS[0] = ATT_SCALE * a0.x; atS[1] = ATT_SCALE * a0.y;
        atS[2] = ATT_SCALE * a0.z; atS[3] = ATT_SCALE * a0.w;
        atS[4] = ATT_SCALE * a1.x; atS[5] = ATT_SCALE * a1.y;
        atS[6] = ATT_SCALE * a1.z; atS[7] = ATT_SCALE * a1.w;
    }
    float xrS[TI][8];
    float drv[TI];
    #pragma unroll
    for (int il = 0; il < TI; ++il) {
        const float* xp = xr + ((size_t)(b * N_ + i0 + il)) * OD + cbase;
        float4 r0 = *(const float4*)(xp);
        float4 r1 = *(const float4*)(xp + 4);
        xrS[il][0] = r0.x; xrS[il][1] = r0.y; xrS[il][2] = r0.z; xrS[il][3] = r0.w;
        xrS[il][4] = r1.x; xrS[il][5] = r1.y; xrS[il][6] = r1.z; xrS[il][7] = r1.w;
        drv[il] = dr[((size_t)(b * N_ + i0 + il)) * H_ + h];  // pre-scaled
    }

    v2f acc[TI][4];
    float sumw[TI];
    #pragma unroll
    for (int il = 0; il < TI; ++il) {
        sumw[il] = 0.f;
        #pragma unroll
        for (int m = 0; m < 4; ++m) acc[il][m] = (v2f){0.f, 0.f};
    }

    // software-pipelined j-loop: j = u*16 + js, u = 0..31
    const float* xlp = xl + ((size_t)(b * N_ + js)) * OD + cbase;
    const int*   ajp = adj + ((size_t)(b * N_ + js)) * N_ + i0;
    const float* dlp = dl + ((size_t)(b * N_ + js)) * H_ + h;

    float4 va = *(const float4*)(xlp);
    float4 vb = *(const float4*)(xlp + 4);
    int2   mj = *(const int2*)(ajp);
    float  dj = *dlp;

    #pragma unroll 2
    for (int u = 0; u < 32; ++u) {
        float4 wa = va, wb = vb;
        int2   wm = mj;
        float  wd = dj;
        if (u < 31) {
            xlp += 16 * OD; ajp += 16 * N_; dlp += 16 * H_;
            va = *(const float4*)(xlp);
            vb = *(const float4*)(xlp + 4);
            mj = *(const int2*)(ajp);
            dj = *dlp;
        }
        const int j = u * 16 + js;
        v2f p0 = (v2f){wa.x, wa.y}, p1 = (v2f){wa.z, wa.w};
        v2f p2 = (v2f){wb.x, wb.y}, p3 = (v2f){wb.z, wb.w};
        int wmv[TI] = {wm.x, wm.y};
        #pragma unroll
        for (int il = 0; il < TI; ++il) {
            float s, e2a = 0.f, e2b = 0.f;
            s = xrS[il][0] + wa.x; e2a = fmaf(atS[0], __builtin_fabsf(s), e2a);
            s = xrS[il][1] + wa.y; e2b = fmaf(atS[1], __builtin_fabsf(s), e2b);
            s = xrS[il][2] + wa.z; e2a = fmaf(atS[2], __builtin_fabsf(s), e2a);
            s = xrS[il][3] + wa.w; e2b = fmaf(atS[3], __builtin_fabsf(s), e2b);
            s = xrS[il][4] + wb.x; e2a = fmaf(atS[4], __builtin_fabsf(s), e2a);
            s = xrS[il][5] + wb.y; e2b = fmaf(atS[5], __builtin_fabsf(s), e2b);
            s = xrS[il][6] + wb.z; e2a = fmaf(atS[6], __builtin_fabsf(s), e2a);
            s = xrS[il][7] + wb.w; e2b = fmaf(atS[7], __builtin_fabsf(s), e2b);
            float eh = e2a + e2b;
            eh = dpp_add<0xB1>(eh);          // + lane^1 (quad_perm 1,0,3,2)
            eh = dpp_add<0x4E>(eh);          // + lane^2 (quad_perm 2,3,0,1)
            float e = (wd + drv[il]) + eh;   // full log2-domain logit
            bool keep = (wmv[il] != 0) || (j == i0 + il);
            float w = keep ? fast_exp2(e) : 0.f;
            sumw[il] += w;
            v2f ws = (v2f){w, w};
            pk_fma(acc[il][0], ws, p0);
            pk_fma(acc[il][1], ws, p1);
            pk_fma(acc[il][2], ws, p2);
            pk_fma(acc[il][3], ws, p3);
        }
    }

    // ---- epilogue: LDS transpose + reduce over the 16 js slices ----
    #pragma unroll
    for (int il = 0; il < TI; ++il) {
        float4 w0 = make_float4(acc[il][0].x, acc[il][0].y,
                                acc[il][1].x, acc[il][1].y);
        float4 w1 = make_float4(acc[il][2].x, acc[il][2].y,
                                acc[il][3].x, acc[il][3].y);
        *(float4*)(&sacc[h][il][js][cq * 8])     = w0;
        *(float4*)(&sacc[h][il][js][cq * 8 + 4]) = w1;
    }
    if (cq == 0) {
        #pragma unroll
        for (int il = 0; il < TI; ++il)
            ssum[h][js][il] = sumw[il];
    }
    __syncthreads();

    const int lane = t & 63;
    const int il2  = lane >> 5;      // target within block
    const int c    = lane & 31;      // channel within head
    float st = 0.f;
    #pragma unroll
    for (int k = 0; k < 16; ++k) st += ssum[h][k][il2];
    float a = 0.f;
    #pragma unroll
    for (int k = 0; k < 16; ++k) a += sacc[h][il2][k][c];
    const float inv = 1.f / st;
    const int cg = h * PH + c;
    out[((size_t)(b * N_ + i0 + il2)) * OD + cg] = fmaf(a, inv, bias[cg]);
}

extern "C" void kernel_launch(void* const* d_in, const int* in_sizes, int n_in,
                              void* d_out, int out_size, void* d_ws, size_t ws_size,
                              hipStream_t stream) {
    const float* x    = (const float*)d_in[0];
    const int*   adj  = (const int*)d_in[1];
    const float* Wl   = (const float*)d_in[2];
    const float* bl   = (const float*)d_in[3];
    const float* Wr   = (const float*)d_in[4];
    const float* br   = (const float*)d_in[5];
    const float* att  = (const float*)d_in[6];
    const float* bias = (const float*)d_in[7];
    float* out = (float*)d_out;

    float* xl = (float*)d_ws;                    // 2 MB
    float* xr = xl + (size_t)B_ * N_ * OD;       // 2 MB
    float* dl = xr + (size_t)B_ * N_ * OD;       // 64 KB
    float* dr = dl + (size_t)B_ * N_ * H_;       // 64 KB

    proj_kernel<<<512, 512, 0, stream>>>(x, Wl, bl, Wr, br, att, xl, xr, dl, dr);
    attn_kernel<<<2048, 256, 0, stream>>>(adj, att, bias, xl, xr, dl, dr, out);
}